// Round 15
// baseline (52.224 us; speedup 1.0000x reference)
//
#include <hip/hip_runtime.h>
#include <math.h>

#define BB 16
#define NN 96
#define HH 256
#define NBIN 11
#define NBPAD 12   // bin row padded to 12 floats
#define IB 2       // i's per block (load amortization)

typedef float f32x4 __attribute__((ext_vector_type(4)));

// ---------------------------------------------------------------------------
// DPP wave64 sum -> wave-uniform scalar. Pure VALU.
// ---------------------------------------------------------------------------
template <int CTRL>
__device__ __forceinline__ float dpp_add(float x) {
    int t = __builtin_amdgcn_update_dpp(0, __float_as_int(x),
                                        CTRL, 0xf, 0xf, true);
    return x + __int_as_float(t);
}

__device__ __forceinline__ float wave64_sum_uniform(float x) {
    x = dpp_add<0x111>(x);  // row_shr:1
    x = dpp_add<0x112>(x);  // row_shr:2
    x = dpp_add<0x114>(x);  // row_shr:4
    x = dpp_add<0x118>(x);  // row_shr:8
    x = dpp_add<0x142>(x);  // row_bcast:15
    x = dpp_add<0x143>(x);  // row_bcast:31
    return __int_as_float(__builtin_amdgcn_readlane(__float_as_int(x), 63));
}

// ---------------------------------------------------------------------------
// Kernel 1: proj[r][k] = sum_h inputs[r][h] * W_atom[h][k] + 0.5*b_bin[k]
// ---------------------------------------------------------------------------
#define ROWS_PER_BLOCK 3

__global__ __launch_bounds__(HH) void proj_kernel(
    const float* __restrict__ inputs,
    const float* __restrict__ W_atom,
    const float* __restrict__ b_bin,
    float* __restrict__ proj)
{
    __shared__ float rows[ROWS_PER_BLOCK][HH];
    const int r0 = blockIdx.x * ROWS_PER_BLOCK;
    const int k  = threadIdx.x;

    #pragma unroll
    for (int r = 0; r < ROWS_PER_BLOCK; ++r)
        rows[r][k] = inputs[(size_t)(r0 + r) * HH + k];
    __syncthreads();

    float acc[ROWS_PER_BLOCK];
    #pragma unroll
    for (int r = 0; r < ROWS_PER_BLOCK; ++r) acc[r] = 0.f;

    #pragma unroll 8
    for (int h = 0; h < HH; ++h) {
        const float w = W_atom[(size_t)h * HH + k];
        #pragma unroll
        for (int r = 0; r < ROWS_PER_BLOCK; ++r)
            acc[r] = fmaf(rows[r][h], w, acc[r]);
    }

    const float halfb = 0.5f * b_bin[k];
    #pragma unroll
    for (int r = 0; r < ROWS_PER_BLOCK; ++r)
        proj[(size_t)(r0 + r) * HH + k] = acc[r] + halfb;
}

// ---------------------------------------------------------------------------
// Kernel 2 (fused pair + score + context), R14 structure + ONE change:
//   1-deep LOAD ROTATION. Iteration t+1's 4 loads are issued BEFORE
//   iteration t's 4 NT stores, so in the per-wave in-order vmcnt FIFO the
//   loads are OLDER than the stores -> consuming them needs only
//   s_waitcnt vmcnt(4), never store retirement. (R12's order forced
//   vmcnt(0) per iteration = compute serialized behind HBM store drain.)
//   Only +16 VGPR (4 float4), no structs, unroll-2 renames the rotation.
// ---------------------------------------------------------------------------
__global__ __launch_bounds__(256, 4) void pair_ctx_kernel(
    const float* __restrict__ inputs,
    const float* __restrict__ bin_features,
    const float* __restrict__ W_bin,
    const float* __restrict__ w_score,
    const float* __restrict__ b_score,
    const float* __restrict__ proj,
    float* __restrict__ atom_pair,
    float* __restrict__ context)
{
    const int blk  = blockIdx.x;           // 0 .. BB*NN/IB-1
    const int b    = blk / (NN / IB);
    const int ip   = blk % (NN / IB);
    const int bi0  = b * NN + IB * ip;     // and bi0+1
    const int lane = threadIdx.x & 63;
    const int wave = threadIdx.x >> 6;     // 0..3
    const int k4   = lane << 2;            // float4 offset into H

    __shared__ float binf[IB * NN * NBPAD];
    __shared__ float partial[3][IB * HH];

    {   // both i's bin rows are contiguous in global: one 8448 B copy
        const float* bp = bin_features + (size_t)bi0 * NN * NBIN;
        for (int t = threadIdx.x; t < IB * NN * NBIN; t += 256)
            binf[(t / NBIN) * NBPAD + (t % NBIN)] = bp[t];
    }

    const float4 in_i0 = *(const float4*)(inputs + (size_t)bi0 * HH + k4);
    const float4 in_i1 = *(const float4*)(inputs + (size_t)(bi0 + 1) * HH + k4);
    const float4 pr_i0 = *(const float4*)(proj   + (size_t)bi0 * HH + k4);
    const float4 pr_i1 = *(const float4*)(proj   + (size_t)(bi0 + 1) * HH + k4);
    const float4 ws    = *(const float4*)(w_score + k4);
    const float  bsc   = b_score[0];

    float4 wb[NBIN];
    #pragma unroll
    for (int c = 0; c < NBIN; ++c)
        wb[c] = *(const float4*)(W_bin + c * HH + k4);

    const float* inb  = inputs + (size_t)b * NN * HH + k4;
    const float* prb  = proj   + (size_t)b * NN * HH + k4;
    float*       apb0 = atom_pair + (size_t)bi0 * NN * HH + k4;
    float*       apb1 = atom_pair + (size_t)(bi0 + 1) * NN * HH + k4;

    // prologue loads for t=0 (issued before the barrier so they fly early)
    float4 cin0 = *(const float4*)(inb + (size_t)(wave)     * HH);
    float4 cin1 = *(const float4*)(inb + (size_t)(wave + 4) * HH);
    float4 cpr0 = *(const float4*)(prb + (size_t)(wave)     * HH);
    float4 cpr1 = *(const float4*)(prb + (size_t)(wave + 4) * HH);

    __syncthreads();                       // binf ready

    float4 acc0 = make_float4(0.f, 0.f, 0.f, 0.f);
    float4 acc1 = make_float4(0.f, 0.f, 0.f, 0.f);

    #pragma unroll 2
    for (int t = 0; t < 12; ++t) {
        const int j0 = wave + 8 * t;       // this step's j's: j0, j0+4

        // ---- issue NEXT iteration's loads FIRST (older than the stores) ---
        float4 nin0, nin1, npr0, npr1;
        if (t < 11) {
            nin0 = *(const float4*)(inb + (size_t)(j0 + 8)  * HH);
            nin1 = *(const float4*)(inb + (size_t)(j0 + 12) * HH);
            npr0 = *(const float4*)(prb + (size_t)(j0 + 8)  * HH);
            npr1 = *(const float4*)(prb + (size_t)(j0 + 12) * HH);
        }

        // ---- stores for current step (NT, bypass L2) ----
        {
            f32x4 ap;
            ap.x = in_i0.x + cin0.x;  ap.y = in_i0.y + cin0.y;
            ap.z = in_i0.z + cin0.z;  ap.w = in_i0.w + cin0.w;
            __builtin_nontemporal_store(ap, (f32x4*)(apb0 + (size_t)j0 * HH));
            ap.x = in_i1.x + cin0.x;  ap.y = in_i1.y + cin0.y;
            ap.z = in_i1.z + cin0.z;  ap.w = in_i1.w + cin0.w;
            __builtin_nontemporal_store(ap, (f32x4*)(apb1 + (size_t)j0 * HH));
            ap.x = in_i0.x + cin1.x;  ap.y = in_i0.y + cin1.y;
            ap.z = in_i0.z + cin1.z;  ap.w = in_i0.w + cin1.w;
            __builtin_nontemporal_store(ap,
                (f32x4*)(apb0 + (size_t)(j0 + 4) * HH));
            ap.x = in_i1.x + cin1.x;  ap.y = in_i1.y + cin1.y;
            ap.z = in_i1.z + cin1.z;  ap.w = in_i1.w + cin1.w;
            __builtin_nontemporal_store(ap,
                (f32x4*)(apb1 + (size_t)(j0 + 4) * HH));
        }

        // ---- compute current step ----
        float part[4];                     // [2u+ii]
        #pragma unroll
        for (int u = 0; u < 2; ++u) {
            const int j = j0 + 4 * u;
            const float4 prj = u ? cpr1 : cpr0;
            #pragma unroll
            for (int ii = 0; ii < 2; ++ii) {
                const float4* bf4 =
                    (const float4*)&binf[(ii * NN + j) * NBPAD];
                const float4 bq0 = bf4[0];
                const float4 bq1 = bf4[1];
                const float4 bq2 = bf4[2];
                const float bc[NBIN] = { bq0.x, bq0.y, bq0.z, bq0.w,
                                         bq1.x, bq1.y, bq1.z, bq1.w,
                                         bq2.x, bq2.y, bq2.z };

                const float4 pri = ii ? pr_i1 : pr_i0;
                float4 v;
                v.x = pri.x + prj.x;  v.y = pri.y + prj.y;
                v.z = pri.z + prj.z;  v.w = pri.w + prj.w;
                #pragma unroll
                for (int c = 0; c < NBIN; ++c) {
                    v.x = fmaf(bc[c], wb[c].x, v.x);
                    v.y = fmaf(bc[c], wb[c].y, v.y);
                    v.z = fmaf(bc[c], wb[c].z, v.z);
                    v.w = fmaf(bc[c], wb[c].w, v.w);
                }
                v.x = fmaxf(v.x, 0.f); v.y = fmaxf(v.y, 0.f);
                v.z = fmaxf(v.z, 0.f); v.w = fmaxf(v.w, 0.f);
                part[2 * u + ii] =
                    v.x * ws.x + v.y * ws.y + v.z * ws.z + v.w * ws.w;
            }
        }

        float s[4];
        #pragma unroll
        for (int p = 0; p < 4; ++p) {
            const float tot = wave64_sum_uniform(part[p]);
            s[p] = __builtin_amdgcn_rcpf(1.f + __expf(-(tot + bsc)));
        }

        acc0.x = fmaf(s[0], cin0.x, acc0.x);
        acc0.y = fmaf(s[0], cin0.y, acc0.y);
        acc0.z = fmaf(s[0], cin0.z, acc0.z);
        acc0.w = fmaf(s[0], cin0.w, acc0.w);
        acc1.x = fmaf(s[1], cin0.x, acc1.x);
        acc1.y = fmaf(s[1], cin0.y, acc1.y);
        acc1.z = fmaf(s[1], cin0.z, acc1.z);
        acc1.w = fmaf(s[1], cin0.w, acc1.w);
        acc0.x = fmaf(s[2], cin1.x, acc0.x);
        acc0.y = fmaf(s[2], cin1.y, acc0.y);
        acc0.z = fmaf(s[2], cin1.z, acc0.z);
        acc0.w = fmaf(s[2], cin1.w, acc0.w);
        acc1.x = fmaf(s[3], cin1.x, acc1.x);
        acc1.y = fmaf(s[3], cin1.y, acc1.y);
        acc1.z = fmaf(s[3], cin1.z, acc1.z);
        acc1.w = fmaf(s[3], cin1.w, acc1.w);

        // ---- rotate ----
        cin0 = nin0; cin1 = nin1; cpr0 = npr0; cpr1 = npr1;
    }

    // cross-wave reduce of both context accumulators
    if (wave > 0) {
        *(float4*)(&partial[wave - 1][k4]) = acc0;
        *(float4*)(&partial[wave - 1][HH + k4]) = acc1;
    }
    __syncthreads();
    if (wave == 0) {
        #pragma unroll
        for (int w = 0; w < 3; ++w) {
            const float4 p0 = *(const float4*)(&partial[w][k4]);
            const float4 p1 = *(const float4*)(&partial[w][HH + k4]);
            acc0.x += p0.x; acc0.y += p0.y; acc0.z += p0.z; acc0.w += p0.w;
            acc1.x += p1.x; acc1.y += p1.y; acc1.z += p1.z; acc1.w += p1.w;
        }
        *(float4*)(context + (size_t)bi0 * HH + k4) = acc0;
        *(float4*)(context + (size_t)(bi0 + 1) * HH + k4) = acc1;
    }
}

extern "C" void kernel_launch(void* const* d_in, const int* in_sizes, int n_in,
                              void* d_out, int out_size, void* d_ws, size_t ws_size,
                              hipStream_t stream)
{
    const float* inputs       = (const float*)d_in[0];   // (B,N,H)
    const float* bin_features = (const float*)d_in[1];   // (B,N,N,BIN)
    const float* W_atom       = (const float*)d_in[2];   // (H,H)
    const float* W_bin        = (const float*)d_in[3];   // (BIN,H)
    const float* b_bin        = (const float*)d_in[4];   // (H,)
    const float* w_score      = (const float*)d_in[5];   // (H,1)
    const float* b_score      = (const float*)d_in[6];   // (1,)

    float* context   = (float*)d_out;                         // B*N*H
    float* atom_pair = (float*)d_out + (size_t)BB * NN * HH;  // B*N*N*H

    float* proj = (float*)d_ws;                               // B*N*H floats

    proj_kernel<<<(BB * NN) / ROWS_PER_BLOCK, HH, 0, stream>>>(
        inputs, W_atom, b_bin, proj);

    pair_ctx_kernel<<<(BB * NN) / IB, 256, 0, stream>>>(
        inputs, bin_features, W_bin, w_score, b_score, proj,
        atom_pair, context);
}

// Round 16
// 48.568 us; speedup vs baseline: 1.0753x; 1.0753x over previous
//
#include <hip/hip_runtime.h>
#include <math.h>

#define BB 16
#define NN 96
#define HH 256
#define NBIN 11
#define IB 2       // i's per block (load amortization)

typedef float f32x4 __attribute__((ext_vector_type(4)));

// ---------------------------------------------------------------------------
// DPP wave64 sum -> wave-uniform scalar. Pure VALU.
// ---------------------------------------------------------------------------
template <int CTRL>
__device__ __forceinline__ float dpp_add(float x) {
    int t = __builtin_amdgcn_update_dpp(0, __float_as_int(x),
                                        CTRL, 0xf, 0xf, true);
    return x + __int_as_float(t);
}

__device__ __forceinline__ float wave64_sum_uniform(float x) {
    x = dpp_add<0x111>(x);  // row_shr:1
    x = dpp_add<0x112>(x);  // row_shr:2
    x = dpp_add<0x114>(x);  // row_shr:4
    x = dpp_add<0x118>(x);  // row_shr:8
    x = dpp_add<0x142>(x);  // row_bcast:15
    x = dpp_add<0x143>(x);  // row_bcast:31
    return __int_as_float(__builtin_amdgcn_readlane(__float_as_int(x), 63));
}

// ---------------------------------------------------------------------------
// Kernel 1: proj[r][k] = sum_h inputs[r][h] * W_atom[h][k] + 0.5*b_bin[k]
// ---------------------------------------------------------------------------
#define ROWS_PER_BLOCK 3

__global__ __launch_bounds__(HH) void proj_kernel(
    const float* __restrict__ inputs,
    const float* __restrict__ W_atom,
    const float* __restrict__ b_bin,
    float* __restrict__ proj)
{
    __shared__ float rows[ROWS_PER_BLOCK][HH];
    const int r0 = blockIdx.x * ROWS_PER_BLOCK;
    const int k  = threadIdx.x;

    #pragma unroll
    for (int r = 0; r < ROWS_PER_BLOCK; ++r)
        rows[r][k] = inputs[(size_t)(r0 + r) * HH + k];
    __syncthreads();

    float acc[ROWS_PER_BLOCK];
    #pragma unroll
    for (int r = 0; r < ROWS_PER_BLOCK; ++r) acc[r] = 0.f;

    #pragma unroll 8
    for (int h = 0; h < HH; ++h) {
        const float w = W_atom[(size_t)h * HH + k];
        #pragma unroll
        for (int r = 0; r < ROWS_PER_BLOCK; ++r)
            acc[r] = fmaf(rows[r][h], w, acc[r]);
    }

    const float halfb = 0.5f * b_bin[k];
    #pragma unroll
    for (int r = 0; r < ROWS_PER_BLOCK; ++r)
        proj[(size_t)(r0 + r) * HH + k] = acc[r] + halfb;
}

// ---------------------------------------------------------------------------
// Kernel 2 (fused pair + score + context), R14 structure + ONE change:
//   bin rows read via WAVE-UNIFORM SCALAR LOADS (s_load) directly from
//   global, instead of LDS staging + 12 ds_read_b128/iter. The bin address
//   depends only on j (wave-uniform; readfirstlane forces scalarization),
//   so values land in SGPRs and feed v_fma as the scalar operand — zero
//   LDS-unit traffic, no staging loop, no barrier A. SMEM pipe is otherwise
//   idle in this kernel.
// ---------------------------------------------------------------------------
__global__ __launch_bounds__(256, 4) void pair_ctx_kernel(
    const float* __restrict__ inputs,
    const float* __restrict__ bin_features,
    const float* __restrict__ W_bin,
    const float* __restrict__ w_score,
    const float* __restrict__ b_score,
    const float* __restrict__ proj,
    float* __restrict__ atom_pair,
    float* __restrict__ context)
{
    const int blk   = blockIdx.x;          // 0 .. BB*NN/IB-1
    const int b     = blk / (NN / IB);
    const int ip    = blk % (NN / IB);
    const int bi0   = b * NN + IB * ip;    // and bi0+1
    const int lane  = threadIdx.x & 63;
    const int wave  = threadIdx.x >> 6;    // 0..3
    const int swave = __builtin_amdgcn_readfirstlane(wave);  // scalar copy
    const int k4    = lane << 2;           // float4 offset into H

    __shared__ float partial[3][IB * HH];  // cross-wave context combine only

    const float4 in_i0 = *(const float4*)(inputs + (size_t)bi0 * HH + k4);
    const float4 in_i1 = *(const float4*)(inputs + (size_t)(bi0 + 1) * HH + k4);
    const float4 pr_i0 = *(const float4*)(proj   + (size_t)bi0 * HH + k4);
    const float4 pr_i1 = *(const float4*)(proj   + (size_t)(bi0 + 1) * HH + k4);
    const float4 ws    = *(const float4*)(w_score + k4);
    const float  bsc   = b_score[0];

    float4 wb[NBIN];
    #pragma unroll
    for (int c = 0; c < NBIN; ++c)
        wb[c] = *(const float4*)(W_bin + c * HH + k4);

    const float* inb  = inputs + (size_t)b * NN * HH + k4;
    const float* prb  = proj   + (size_t)b * NN * HH + k4;
    float*       apb0 = atom_pair + (size_t)bi0 * NN * HH + k4;
    float*       apb1 = atom_pair + (size_t)(bi0 + 1) * NN * HH + k4;

    // wave-uniform scalar bases for the two bin row streams
    const float* bin0 = bin_features + (size_t)bi0 * NN * NBIN;
    const float* bin1 = bin_features + (size_t)(bi0 + 1) * NN * NBIN;

    float4 acc0 = make_float4(0.f, 0.f, 0.f, 0.f);
    float4 acc1 = make_float4(0.f, 0.f, 0.f, 0.f);

    // j = swave + 4*u + 8*t, u in {0,1}, t in [0,12) covers [0,96)
    for (int t = 0; t < 12; ++t) {
        const int j0 = swave + 8 * t;      // scalar; j's this step: j0, j0+4

        float4 inj[2], prj[2];
        #pragma unroll
        for (int u = 0; u < 2; ++u) {
            inj[u] = *(const float4*)(inb + (size_t)(j0 + 4 * u) * HH);
            prj[u] = *(const float4*)(prb + (size_t)(j0 + 4 * u) * HH);
        }

        #pragma unroll
        for (int u = 0; u < 2; ++u) {
            f32x4 ap;
            ap.x = in_i0.x + inj[u].x;  ap.y = in_i0.y + inj[u].y;
            ap.z = in_i0.z + inj[u].z;  ap.w = in_i0.w + inj[u].w;
            __builtin_nontemporal_store(
                ap, (f32x4*)(apb0 + (size_t)(j0 + 4 * u) * HH));
            ap.x = in_i1.x + inj[u].x;  ap.y = in_i1.y + inj[u].y;
            ap.z = in_i1.z + inj[u].z;  ap.w = in_i1.w + inj[u].w;
            __builtin_nontemporal_store(
                ap, (f32x4*)(apb1 + (size_t)(j0 + 4 * u) * HH));
        }

        float part[4];                     // [2u+ii]
        #pragma unroll
        for (int u = 0; u < 2; ++u) {
            const int j = j0 + 4 * u;      // scalar
            #pragma unroll
            for (int ii = 0; ii < 2; ++ii) {
                // wave-uniform scalar pointer -> s_load into SGPRs
                const float* bp = (ii ? bin1 : bin0) + (size_t)j * NBIN;

                const float4 pri = ii ? pr_i1 : pr_i0;
                float4 v;
                v.x = pri.x + prj[u].x;  v.y = pri.y + prj[u].y;
                v.z = pri.z + prj[u].z;  v.w = pri.w + prj[u].w;
                #pragma unroll
                for (int c = 0; c < NBIN; ++c) {
                    const float bc = bp[c];   // SGPR operand of v_fma
                    v.x = fmaf(bc, wb[c].x, v.x);
                    v.y = fmaf(bc, wb[c].y, v.y);
                    v.z = fmaf(bc, wb[c].z, v.z);
                    v.w = fmaf(bc, wb[c].w, v.w);
                }
                v.x = fmaxf(v.x, 0.f); v.y = fmaxf(v.y, 0.f);
                v.z = fmaxf(v.z, 0.f); v.w = fmaxf(v.w, 0.f);
                part[2 * u + ii] =
                    v.x * ws.x + v.y * ws.y + v.z * ws.z + v.w * ws.w;
            }
        }

        // four independent DPP reduce chains (2 j x 2 i), pure VALU
        float s[4];
        #pragma unroll
        for (int p = 0; p < 4; ++p) {
            const float tot = wave64_sum_uniform(part[p]);
            s[p] = __builtin_amdgcn_rcpf(1.f + __expf(-(tot + bsc)));
        }

        #pragma unroll
        for (int u = 0; u < 2; ++u) {
            acc0.x = fmaf(s[2 * u],     inj[u].x, acc0.x);
            acc0.y = fmaf(s[2 * u],     inj[u].y, acc0.y);
            acc0.z = fmaf(s[2 * u],     inj[u].z, acc0.z);
            acc0.w = fmaf(s[2 * u],     inj[u].w, acc0.w);
            acc1.x = fmaf(s[2 * u + 1], inj[u].x, acc1.x);
            acc1.y = fmaf(s[2 * u + 1], inj[u].y, acc1.y);
            acc1.z = fmaf(s[2 * u + 1], inj[u].z, acc1.z);
            acc1.w = fmaf(s[2 * u + 1], inj[u].w, acc1.w);
        }
    }

    // cross-wave reduce of both context accumulators
    if (wave > 0) {
        *(float4*)(&partial[wave - 1][k4]) = acc0;
        *(float4*)(&partial[wave - 1][HH + k4]) = acc1;
    }
    __syncthreads();
    if (wave == 0) {
        #pragma unroll
        for (int w = 0; w < 3; ++w) {
            const float4 p0 = *(const float4*)(&partial[w][k4]);
            const float4 p1 = *(const float4*)(&partial[w][HH + k4]);
            acc0.x += p0.x; acc0.y += p0.y; acc0.z += p0.z; acc0.w += p0.w;
            acc1.x += p1.x; acc1.y += p1.y; acc1.z += p1.z; acc1.w += p1.w;
        }
        *(float4*)(context + (size_t)bi0 * HH + k4) = acc0;
        *(float4*)(context + (size_t)(bi0 + 1) * HH + k4) = acc1;
    }
}

extern "C" void kernel_launch(void* const* d_in, const int* in_sizes, int n_in,
                              void* d_out, int out_size, void* d_ws, size_t ws_size,
                              hipStream_t stream)
{
    const float* inputs       = (const float*)d_in[0];   // (B,N,H)
    const float* bin_features = (const float*)d_in[1];   // (B,N,N,BIN)
    const float* W_atom       = (const float*)d_in[2];   // (H,H)
    const float* W_bin        = (const float*)d_in[3];   // (BIN,H)
    const float* b_bin        = (const float*)d_in[4];   // (H,)
    const float* w_score      = (const float*)d_in[5];   // (H,1)
    const float* b_score      = (const float*)d_in[6];   // (1,)

    float* context   = (float*)d_out;                         // B*N*H
    float* atom_pair = (float*)d_out + (size_t)BB * NN * HH;  // B*N*N*H

    float* proj = (float*)d_ws;                               // B*N*H floats

    proj_kernel<<<(BB * NN) / ROWS_PER_BLOCK, HH, 0, stream>>>(
        inputs, W_atom, b_bin, proj);

    pair_ctx_kernel<<<(BB * NN) / IB, 256, 0, stream>>>(
        inputs, bin_features, W_bin, w_score, b_score, proj,
        atom_pair, context);
}